// Round 1
// baseline (470.063 us; speedup 1.0000x reference)
//
#include <hip/hip_runtime.h>
#include <stdint.h>

#define DM   1024
#define HD   64
#define SEQ  2048
#define NB   4
#define MR   8192   // NB*SEQ

typedef __bf16  bf16x8 __attribute__((ext_vector_type(8)));
typedef float   f32x4  __attribute__((ext_vector_type(4)));
typedef unsigned short u16x8 __attribute__((ext_vector_type(8)));
typedef unsigned short u16x4 __attribute__((ext_vector_type(4)));

__device__ __forceinline__ unsigned short f2bf(float f) {
  union { float f; unsigned u; } x; x.f = f;
  unsigned u = x.u + 0x7fffu + ((x.u >> 16) & 1u);   // RTNE
  return (unsigned short)(u >> 16);
}

__device__ __forceinline__ void gld_lds16(const void* g, void* l) {
  __builtin_amdgcn_global_load_lds((const __attribute__((address_space(1))) unsigned int*)g,
                                   (__attribute__((address_space(3))) unsigned int*)l, 16, 0, 0);
}

// ---------------- prep kernels ----------------
__global__ __launch_bounds__(256) void cvt3(const float* __restrict__ a, const float* __restrict__ b,
                                            const float* __restrict__ c, unsigned short* __restrict__ oa,
                                            unsigned short* __restrict__ ob, unsigned short* __restrict__ oc) {
  const float* in = (blockIdx.z == 0) ? a : (blockIdx.z == 1) ? b : c;
  unsigned short* out = (blockIdx.z == 0) ? oa : (blockIdx.z == 1) ? ob : oc;
  size_t i = ((size_t)blockIdx.x * 256 + threadIdx.x) * 8;
  float4 x = *(const float4*)(in + i);
  float4 y = *(const float4*)(in + i + 4);
  u16x8 r = { f2bf(x.x), f2bf(x.y), f2bf(x.z), f2bf(x.w), f2bf(y.x), f2bf(y.y), f2bf(y.z), f2bf(y.w) };
  *(u16x8*)(out + i) = r;
}

// Wq/Wk/Wv [H, D, hd] -> Wt[z][n = h*64+k][d]  (bt layout for GEMM)
__global__ __launch_bounds__(256) void wtrans(const float* __restrict__ wq, const float* __restrict__ wk,
                                              const float* __restrict__ wv, unsigned short* __restrict__ wt) {
  const float* in = (blockIdx.z == 0) ? wq : (blockIdx.z == 1) ? wk : wv;
  int idx = blockIdx.x * 256 + threadIdx.x;   // n*1024 + d
  int n = idx >> 10, d = idx & 1023;
  float v = in[((n >> 6) << 16) + (d << 6) + (n & 63)];
  wt[((size_t)blockIdx.z << 20) + idx] = f2bf(v);
}

__global__ __launch_bounds__(256) void cvt1(const float* __restrict__ in, unsigned short* __restrict__ out) {
  size_t i = ((size_t)blockIdx.x * 256 + threadIdx.x) * 8;
  float4 x = *(const float4*)(in + i);
  float4 y = *(const float4*)(in + i + 4);
  u16x8 r = { f2bf(x.x), f2bf(x.y), f2bf(x.z), f2bf(x.w), f2bf(y.x), f2bf(y.y), f2bf(y.z), f2bf(y.w) };
  *(u16x8*)(out + i) = r;
}

// ---------------- GEMM: C[M,N] = A[M,K] * Bt[N,K]^T ----------------
// M=8192 N=1024 K=1024. 128x128 tile, BK=64, 4 waves (2x2 quadrants of 64x64).
// LDS rows are 128B (8 chunks of 16B); chunk XOR-swizzled by (row&7) so both the
// lane->slot mapping of global_load_lds (no padding allowed) and ds_read_b128
// fragment reads stay at free 2-way bank aliasing.
template <bool BF16OUT>
__global__ __launch_bounds__(256, 2) void gemm_bt(
    const unsigned short* __restrict__ A0, const unsigned short* __restrict__ A1,
    const unsigned short* __restrict__ A2, const unsigned short* __restrict__ Bt,
    void* __restrict__ Cv, const float* __restrict__ bias) {
  __shared__ char lds[32768];
  char* ldsA = lds;
  char* ldsB = lds + 16384;

  const int tid = threadIdx.x, w = tid >> 6, l = tid & 63;
  const int quad = l >> 4, l15 = l & 15;
  const int z = blockIdx.z;
  const unsigned short* A = (z == 0) ? A0 : (z == 1) ? A1 : A2;
  const unsigned short* B = Bt + (size_t)z * (DM * DM);
  const int bm = blockIdx.y * 128, bn = blockIdx.x * 128;
  const int wrow = (w >> 1) * 64, wcol = (w & 1) * 64;

  const int srow = w * 32 + (l >> 3);                // staging row (+p*8)
  const int sc   = ((l & 7) ^ ((l >> 3) & 7)) * 8;   // swizzled k-offset (elems)
  char* ldsAw = ldsA + (w * 32) * 128;
  char* ldsBw = ldsB + (w * 32) * 128;

  f32x4 acc[4][4];
#pragma unroll
  for (int i = 0; i < 4; ++i)
#pragma unroll
    for (int j = 0; j < 4; ++j) acc[i][j] = (f32x4){0.f, 0.f, 0.f, 0.f};

  for (int kt = 0; kt < DM; kt += 64) {
#pragma unroll
    for (int p = 0; p < 4; ++p) {
      gld_lds16(A + (size_t)(bm + srow + p * 8) * DM + kt + sc, ldsAw + p * 1024);
      gld_lds16(B + (size_t)(bn + srow + p * 8) * DM + kt + sc, ldsBw + p * 1024);
    }
    __syncthreads();
#pragma unroll
    for (int ks = 0; ks < 2; ++ks) {
      bf16x8 af[4], bfr[4];
#pragma unroll
      for (int mt = 0; mt < 4; ++mt) {
        int r = wrow + mt * 16 + l15;
        af[mt] = *(const bf16x8*)(ldsA + r * 128 + (((ks * 4 + quad) ^ (r & 7)) * 16));
      }
#pragma unroll
      for (int nt = 0; nt < 4; ++nt) {
        int r = wcol + nt * 16 + l15;
        bfr[nt] = *(const bf16x8*)(ldsB + r * 128 + (((ks * 4 + quad) ^ (r & 7)) * 16));
      }
#pragma unroll
      for (int mt = 0; mt < 4; ++mt)
#pragma unroll
        for (int nt = 0; nt < 4; ++nt)
          acc[mt][nt] = __builtin_amdgcn_mfma_f32_16x16x32_bf16(af[mt], bfr[nt], acc[mt][nt], 0, 0, 0);
    }
    __syncthreads();
  }

  if constexpr (BF16OUT) {
    unsigned short* C = (unsigned short*)Cv + (size_t)z * ((size_t)MR * DM);
#pragma unroll
    for (int mt = 0; mt < 4; ++mt)
#pragma unroll
      for (int r = 0; r < 4; ++r) {
        size_t row = bm + wrow + mt * 16 + quad * 4 + r;
#pragma unroll
        for (int nt = 0; nt < 4; ++nt)
          C[row * DM + bn + wcol + nt * 16 + l15] = f2bf(acc[mt][nt][r]);
      }
  } else {
    float* C = (float*)Cv;
    float bv[4];
#pragma unroll
    for (int nt = 0; nt < 4; ++nt) bv[nt] = bias[bn + wcol + nt * 16 + l15];
#pragma unroll
    for (int mt = 0; mt < 4; ++mt)
#pragma unroll
      for (int r = 0; r < 4; ++r) {
        size_t row = bm + wrow + mt * 16 + quad * 4 + r;
#pragma unroll
        for (int nt = 0; nt < 4; ++nt)
          C[row * DM + bn + wcol + nt * 16 + l15] = acc[mt][nt][r] + bv[nt];
      }
  }
}

// ---------------- flash attention ----------------
// Q/K/V/Ctx layout: [B*S, 1024] bf16, head h at cols [h*64, h*64+64).
// Block = (q-tile of 128 rows) x (b,h). 4 waves, wave w owns q rows [32w,32w+32).
// Per iter: stage K-tile (global_load_lds, swizzled) + V^T tile (packed b64 writes),
// QK^T MFMA -> online softmax (exp2 domain) -> P to swizzled LDS (C->A layout) -> PV MFMA.
__global__ __launch_bounds__(256, 2) void attn_flash(
    const unsigned short* __restrict__ Qp, const unsigned short* __restrict__ Kp,
    const unsigned short* __restrict__ Vp, unsigned short* __restrict__ Ctx) {
  __shared__ char lds[65536];
  char* ldsK  = lds;            // 16KB: K[128][64] swizzled
  char* ldsVt = lds + 16384;    // 16KB: V^T[64][128] swizzled
  char* ldsP  = lds + 32768;    // 32KB: P[128][128] swizzled

  const int tid = threadIdx.x, w = tid >> 6, l = tid & 63;
  const int quad = l >> 4, l15 = l & 15;
  const int qt = blockIdx.x, bh = blockIdx.y;
  const int b = bh >> 4, h = bh & 15;
  const size_t rb = (size_t)b * SEQ;
  const int hc = h * HD;

  bf16x8 qf[2][2];
  const int q0 = qt * 128 + w * 32;
#pragma unroll
  for (int mt = 0; mt < 2; ++mt)
#pragma unroll
    for (int ks = 0; ks < 2; ++ks)
      qf[mt][ks] = *(const bf16x8*)(Qp + (rb + q0 + mt * 16 + l15) * DM + hc + ks * 32 + quad * 8);

  float m_r[2][4], l_r[2][4];
  f32x4 o[2][4];
#pragma unroll
  for (int mt = 0; mt < 2; ++mt)
#pragma unroll
    for (int r = 0; r < 4; ++r) { m_r[mt][r] = -1e30f; l_r[mt][r] = 0.f; }
#pragma unroll
  for (int mt = 0; mt < 2; ++mt)
#pragma unroll
    for (int nt = 0; nt < 4; ++nt) o[mt][nt] = (f32x4){0.f, 0.f, 0.f, 0.f};

  const int srow = w * 32 + (l >> 3);
  const int sc   = ((l & 7) ^ ((l >> 3) & 7)) * 8;
  char* ldsKw = ldsK + (w * 32) * 128;
  const int vt0 = (tid & 31) * 4;    // t base (4 rows)
  const int vn0 = (tid >> 5) * 8;    // n base (8 cols)
  const float c2 = 0.045084220027780106f;  // (1/sqrt(1024)) * log2(e)

  for (int kt = 0; kt < SEQ / 128; ++kt) {
    const int kr = kt * 128;
#pragma unroll
    for (int p = 0; p < 4; ++p)
      gld_lds16(Kp + (rb + kr + srow + p * 8) * DM + hc + sc, ldsKw + p * 1024);

    // V^T staging: 4 rows x 8 cols per thread, packed 4-wide b64 writes
    u16x8 vr[4];
#pragma unroll
    for (int j = 0; j < 4; ++j)
      vr[j] = *(const u16x8*)(Vp + (rb + kr + vt0 + j) * DM + hc + vn0);
#pragma unroll
    for (int i = 0; i < 8; ++i) {
      int n = vn0 + i;
      u16x4 pk = { vr[0][i], vr[1][i], vr[2][i], vr[3][i] };
      *(u16x4*)(ldsVt + n * 256 + (((vt0 >> 3) ^ (n & 7)) * 16) + (vt0 & 7) * 2) = pk;
    }
    __syncthreads();

    // S = Q K^T  (C-layout: row = quad*4+r, col(key) = l15 + 16*ct)
    f32x4 s[2][8];
#pragma unroll
    for (int mt = 0; mt < 2; ++mt)
#pragma unroll
      for (int ct = 0; ct < 8; ++ct) s[mt][ct] = (f32x4){0.f, 0.f, 0.f, 0.f};
#pragma unroll
    for (int ks = 0; ks < 2; ++ks)
#pragma unroll
      for (int ct = 0; ct < 8; ++ct) {
        int rt = ct * 16 + l15;
        bf16x8 kf = *(const bf16x8*)(ldsK + rt * 128 + (((ks * 4 + quad) ^ (rt & 7)) * 16));
        s[0][ct] = __builtin_amdgcn_mfma_f32_16x16x32_bf16(qf[0][ks], kf, s[0][ct], 0, 0, 0);
        s[1][ct] = __builtin_amdgcn_mfma_f32_16x16x32_bf16(qf[1][ks], kf, s[1][ct], 0, 0, 0);
      }

    // online softmax (log2 domain); row-reduce over 8 ct locally + 16 lanes of quad
#pragma unroll
    for (int mt = 0; mt < 2; ++mt) {
#pragma unroll
      for (int r = 0; r < 4; ++r) {
        float mx = s[mt][0][r];
#pragma unroll
        for (int ct = 1; ct < 8; ++ct) mx = fmaxf(mx, s[mt][ct][r]);
#pragma unroll
        for (int sh = 1; sh < 16; sh <<= 1) mx = fmaxf(mx, __shfl_xor(mx, sh));
        float mn = fmaxf(m_r[mt][r], mx * c2);
        float al = exp2f(m_r[mt][r] - mn);
        m_r[mt][r] = mn;
        float rs = 0.f;
#pragma unroll
        for (int ct = 0; ct < 8; ++ct) {
          float p = exp2f(s[mt][ct][r] * c2 - mn);
          s[mt][ct][r] = p;
          rs += p;
        }
#pragma unroll
        for (int sh = 1; sh < 16; sh <<= 1) rs += __shfl_xor(rs, sh);
        l_r[mt][r] = l_r[mt][r] * al + rs;
#pragma unroll
        for (int nt = 0; nt < 4; ++nt) o[mt][nt][r] *= al;
      }
    }

    // P (C-layout regs) -> LDS bf16 in A-readable swizzled layout (wave-private rows)
#pragma unroll
    for (int mt = 0; mt < 2; ++mt)
#pragma unroll
      for (int ct = 0; ct < 8; ++ct) {
        int colb = ct * 16 + l15;
        int ch = colb >> 3;
#pragma unroll
        for (int r = 0; r < 4; ++r) {
          int row = w * 32 + mt * 16 + quad * 4 + r;
          *(unsigned short*)(ldsP + row * 256 + ((ch ^ (row & 7)) * 16) + (colb & 7) * 2) = f2bf(s[mt][ct][r]);
        }
      }

    // O += P * V
#pragma unroll
    for (int ks = 0; ks < 4; ++ks) {
      bf16x8 pf[2];
#pragma unroll
      for (int mt = 0; mt < 2; ++mt) {
        int row = w * 32 + mt * 16 + l15;
        pf[mt] = *(const bf16x8*)(ldsP + row * 256 + (((ks * 4 + quad) ^ (row & 7)) * 16));
      }
#pragma unroll
      for (int nt = 0; nt < 4; ++nt) {
        int n = nt * 16 + l15;
        bf16x8 vf = *(const bf16x8*)(ldsVt + n * 256 + (((ks * 4 + quad) ^ (n & 7)) * 16));
        o[0][nt] = __builtin_amdgcn_mfma_f32_16x16x32_bf16(pf[0], vf, o[0][nt], 0, 0, 0);
        o[1][nt] = __builtin_amdgcn_mfma_f32_16x16x32_bf16(pf[1], vf, o[1][nt], 0, 0, 0);
      }
    }
    __syncthreads();
  }

#pragma unroll
  for (int mt = 0; mt < 2; ++mt)
#pragma unroll
    for (int r = 0; r < 4; ++r) {
      float inv = 1.f / l_r[mt][r];
      size_t row = rb + q0 + mt * 16 + quad * 4 + r;
#pragma unroll
      for (int nt = 0; nt < 4; ++nt)
        Ctx[row * DM + hc + nt * 16 + l15] = f2bf(o[mt][nt][r] * inv);
    }
}

// ---------------- launch ----------------
extern "C" void kernel_launch(void* const* d_in, const int* in_sizes, int n_in,
                              void* d_out, int out_size, void* d_ws, size_t ws_size,
                              hipStream_t stream) {
  const float* query  = (const float*)d_in[0];
  const float* key_in = (const float*)d_in[1];
  const float* value  = (const float*)d_in[2];
  const float* Wq = (const float*)d_in[3];
  const float* Wk = (const float*)d_in[4];
  const float* Wv = (const float*)d_in[5];
  const float* Wo = (const float*)d_in[6];
  const float* bo = (const float*)d_in[7];
  float* out = (float*)d_out;

  unsigned short* ws = (unsigned short*)d_ws;
  const size_t NT = (size_t)MR * DM;   // 8388608 elems
  unsigned short* Xq  = ws;
  unsigned short* Xk  = Xq + NT;
  unsigned short* Xv  = Xk + NT;
  unsigned short* Wt  = Xv + NT;              // 3 * 1M
  unsigned short* Wob = Wt + 3 * 1048576;     // 1M
  unsigned short* Qb  = Wob + 1048576;
  unsigned short* Kb  = Qb + NT;
  unsigned short* Vb  = Kb + NT;
  unsigned short* Cx  = Vb + NT;
  // total: 7*16MB + 8MB = ~126MB of ws

  cvt3<<<dim3(4096, 1, 3), 256, 0, stream>>>(query, key_in, value, Xq, Xk, Xv);
  wtrans<<<dim3(4096, 1, 3), 256, 0, stream>>>(Wq, Wk, Wv, Wt);
  cvt1<<<dim3(512, 1, 1), 256, 0, stream>>>(Wo, Wob);
  gemm_bt<true><<<dim3(8, 64, 3), 256, 0, stream>>>(Xq, Xk, Xv, Wt, Qb, nullptr);
  attn_flash<<<dim3(16, 64), 256, 0, stream>>>(Qb, Kb, Vb, Cx);
  gemm_bt<false><<<dim3(8, 64, 1), 256, 0, stream>>>(Cx, Cx, Cx, Wob, out, bo);
}